// Round 5
// baseline (177.185 us; speedup 1.0000x reference)
//
#include <hip/hip_runtime.h>
#include <hip/hip_bf16.h>
#include <stdint.h>

#define T_DIM 256
#define B_DIM 128
#define I_DIM 512
#define H_DIM 1024
#define M_DIM (T_DIM * B_DIM)

typedef __attribute__((ext_vector_type(4))) float f32x4;
typedef __attribute__((ext_vector_type(8))) short short8;  // 8 bf16 in 4 VGPRs

__device__ inline unsigned short f2bf(float f) {
    __hip_bfloat16 h = __float2bfloat16(f);  // RNE
    unsigned short u;
    __builtin_memcpy(&u, &h, sizeof(u));
    return u;
}

// async 16B global -> LDS (direct). LDS dest is wave-uniform base + lane*16
// (lane-linear); swizzle is baked into the GLOBAL source layout (pack_both).
__device__ inline void gload_lds16(const void* g, void* l) {
    __builtin_amdgcn_global_load_lds(
        (const __attribute__((address_space(1))) uint32_t*)g,
        (__attribute__((address_space(3))) uint32_t*)l, 16, 0, 0);
}

// ---------------------------------------------------------------------------
// pack_both: f32 rows (stride 512) -> bf16 swizzled 128-row tile images.
// Tiles 0..255 = x (M_DIM rows), tiles 256..263 = W_ih (H_DIM rows).
// Image granule layout per tile: [kst][row][slot], granule (r,s) holds src
// cols kst*64 + (s^(r&7))*8 .. +8. GEMM stages linearly via gload_lds and
// reads granule g of row r at slot g^(r&7) (<=2-way bank alias, free).
// ---------------------------------------------------------------------------
__global__ void pack_both(const float* __restrict__ x,
                          const float* __restrict__ W,
                          unsigned short* __restrict__ dst) {
    int id = blockIdx.x * 256 + threadIdx.x;  // 0 .. 264*8192-1
    int slot = id & 7;
    int row = (id >> 3) & 127;
    int kst = (id >> 10) & 7;
    int tile = id >> 13;
    int g = slot ^ (row & 7);
    const float* base = (tile < 256) ? (x + (size_t)tile * 128 * I_DIM)
                                     : (W + (size_t)(tile - 256) * 128 * I_DIM);
    const float* s = base + (size_t)row * I_DIM + kst * 64 + g * 8;
    f32x4 lo = *(const f32x4*)s;
    f32x4 hi = *(const f32x4*)(s + 4);
    union { unsigned short us[8]; short8 v; } pk;
#pragma unroll
    for (int j = 0; j < 4; ++j) { pk.us[j] = f2bf(lo[j]); pk.us[4 + j] = f2bf(hi[j]); }
    *(short8*)(dst + (size_t)id * 8) = pk.v;
}

// ---------------------------------------------------------------------------
// bias_dot: biasall[b][h] = hidden[b,:].W_hh[h,:] + b_ih[h] + b_hh[h], f32
// exact. One thread per output; 512 blocks; pure VALU + cache-friendly
// (hidden rows broadcast across 1024 threads, W_hh streamed once).
// ---------------------------------------------------------------------------
__global__ __launch_bounds__(256) void bias_dot(
    const float* __restrict__ hidden, const float* __restrict__ W_hh,
    const float* __restrict__ b_ih, const float* __restrict__ b_hh,
    float* __restrict__ biasall) {
    int id = blockIdx.x * 256 + threadIdx.x;  // 0..131071
    int b = id >> 10, h = id & 1023;
    const float* hr = hidden + (size_t)b * H_DIM;
    const float* wr = W_hh + (size_t)h * H_DIM;
    float s = 0.f;
#pragma unroll 4
    for (int k = 0; k < H_DIM; k += 4) {
        f32x4 a = *(const f32x4*)(hr + k);
        f32x4 w = *(const f32x4*)(wr + k);
        s += a[0] * w[0] + a[1] * w[1] + a[2] * w[2] + a[3] * w[3];
    }
    biasall[id] = s + b_ih[h] + b_hh[h];
}

// ---------------------------------------------------------------------------
// gemm256: out[m][h] = relu(Xp[m].Wp[h] + biasall[m&127][h]).
// 256x256 tile, BK=64, 512 thr = 8 waves (2M x 4N), 16x16x32 bf16 MFMA,
// 64 MFMA/wave/K-step. LDS 128 KB double-buffered; counted s_waitcnt
// vmcnt(8): next K-tile's 8 gload_lds stay in flight across barriers;
// staging into a buffer only after the barrier that frees it.
// ---------------------------------------------------------------------------
__global__ __launch_bounds__(512, 1) void gemm256(
    const unsigned short* __restrict__ Xp, const unsigned short* __restrict__ Wp,
    const float* __restrict__ biasall, float* __restrict__ C,
    float* __restrict__ Clast) {
    __shared__ unsigned short As[2][2][8192];  // [buf][128-row half][128*64]
    __shared__ unsigned short Bs[2][2][8192];

    const int tid = threadIdx.x;
    const int lane = tid & 63;
    const int wid = tid >> 6;
    const int wm = wid >> 2, wn = wid & 3;   // 2 x 4 wave grid
    const int llo = lane & 15, lhi = lane >> 4;

    // XCD-aware swizzle (grid = 512, divisible by 8)
    const int orig = blockIdx.x;
    const int wg = (orig & 7) * 64 + (orig >> 3);
    const int mt = wg >> 2;                  // 128 m-tiles
    const int nt = wg & 3;                   // 4 n-tiles
    const int m0 = mt * 256;
    const int n0 = nt * 256;

    const unsigned short* Ab = Xp + (size_t)(2 * mt) * 65536 + (size_t)tid * 8;
    const unsigned short* Bb = Wp + (size_t)(2 * nt) * 65536 + (size_t)tid * 8;

    auto stage = [&](int kt, int buf) {
#pragma unroll
        for (int img = 0; img < 2; ++img)
#pragma unroll
            for (int part = 0; part < 2; ++part) {
                gload_lds16(Ab + (size_t)img * 65536 + kt * 8192 + part * 4096,
                            (char*)&As[buf][img][0] + part * 8192 + tid * 16);
                gload_lds16(Bb + (size_t)img * 65536 + kt * 8192 + part * 4096,
                            (char*)&Bs[buf][img][0] + part * 8192 + tid * 16);
            }
    };

    f32x4 acc[8][4] = {};

    auto compute = [&](int buf) {
        __builtin_amdgcn_s_setprio(1);
#pragma unroll
        for (int ks = 0; ks < 2; ++ks) {
            short8 bfv[4];
#pragma unroll
            for (int ni = 0; ni < 4; ++ni) {
                int rB = (wn & 1) * 64 + ni * 16 + llo;
                int g = ks * 4 + lhi;
                bfv[ni] = *(const short8*)&Bs[buf][wn >> 1]
                                             [rB * 64 + ((g ^ (rB & 7)) << 3)];
            }
#pragma unroll
            for (int mh = 0; mh < 2; ++mh) {  // two 16-MFMA phases per ks
                short8 af[4];
#pragma unroll
                for (int mi4 = 0; mi4 < 4; ++mi4) {
                    int r = (mh * 4 + mi4) * 16 + llo;
                    int g = ks * 4 + lhi;
                    af[mi4] = *(const short8*)&As[buf][wm]
                                                 [r * 64 + ((g ^ (r & 7)) << 3)];
                }
#pragma unroll
                for (int mi4 = 0; mi4 < 4; ++mi4)
#pragma unroll
                    for (int ni = 0; ni < 4; ++ni)
                        acc[mh * 4 + mi4][ni] = __builtin_amdgcn_mfma_f32_16x16x32_bf16(
                            af[mi4], bfv[ni], acc[mh * 4 + mi4][ni], 0, 0, 0);
            }
        }
        __builtin_amdgcn_s_setprio(0);
    };

    stage(0, 0);  // 8 loads in flight
    stage(1, 1);  // 16 in flight
#pragma unroll
    for (int kt = 0; kt < 8; ++kt) {
        const int buf = kt & 1;
        if (kt < 7)
            asm volatile("s_waitcnt vmcnt(8)" ::: "memory");  // tile kt landed
        else
            asm volatile("s_waitcnt vmcnt(0)" ::: "memory");
        asm volatile("s_barrier" ::: "memory");
        __builtin_amdgcn_sched_barrier(0);
        compute(buf);
        __builtin_amdgcn_sched_barrier(0);
        asm volatile("s_barrier" ::: "memory");   // buf free for reuse
        if (kt + 2 < 8) stage(kt + 2, buf);       // stays in flight across iters
    }

    // epilogue: bias + relu + store (+ out_last copy from final 128 rows)
    const bool last_tile = (mt == 127);
#pragma unroll
    for (int mi = 0; mi < 8; ++mi) {
#pragma unroll
        for (int ni = 0; ni < 4; ++ni) {
            int col = n0 + wn * 64 + ni * 16 + llo;
            int rowb = m0 + wm * 128 + mi * 16 + lhi * 4;
#pragma unroll
            for (int r = 0; r < 4; ++r) {
                int row = rowb + r;
                float v = acc[mi][ni][r] + biasall[(row & 127) * H_DIM + col];
                v = fmaxf(v, 0.0f);
                C[(size_t)row * H_DIM + col] = v;
                if (last_tile && row >= M_DIM - 128)
                    Clast[(row & 127) * H_DIM + col] = v;
            }
        }
    }
}

// ---------------------------------------------------------------------------
// Fallback reg-staged f32 GEMM (known-correct) if ws is too small.
// ---------------------------------------------------------------------------
__global__ __launch_bounds__(256, 2) void gemm_bt(
    const float* __restrict__ A, const float* __restrict__ Bm,
    int M, int N, int K,
    const float* __restrict__ bias0,
    float* __restrict__ C, float* __restrict__ Clast) {
    __shared__ unsigned short As[128 * 64];
    __shared__ unsigned short Bs[128 * 64];

    const int tid = threadIdx.x;
    const int wid = tid >> 6;
    const int lane = tid & 63;
    const int wr = wid >> 1, wc = wid & 1;
    const int lhi = lane >> 4;
    const int llo = lane & 15;

    const int orig = blockIdx.x;
    const int nwg = gridDim.x;
    const int wg = (nwg > 8 && (nwg & 7) == 0)
                       ? ((orig & 7) * (nwg >> 3) + (orig >> 3))
                       : orig;
    const int m0 = (wg >> 3) * 128;
    const int n0 = (wg & 7) * 128;

    const int srow = tid >> 3;
    const int c8 = tid & 7;
    const int slot8 = (c8 ^ (srow & 7)) * 8;

    const float* Aptr = A + (size_t)(m0 + srow) * K + c8 * 8;
    const float* Bptr = Bm + (size_t)(n0 + srow) * K + c8 * 8;

    f32x4 pf[2][4][2];

    auto issue = [&](int k0) {
#pragma unroll
        for (int g = 0; g < 4; ++g) {
            const float* pa = Aptr + (size_t)g * 32 * K + k0;
            const float* pb = Bptr + (size_t)g * 32 * K + k0;
            pf[0][g][0] = *(const f32x4*)pa;
            pf[0][g][1] = *(const f32x4*)(pa + 4);
            pf[1][g][0] = *(const f32x4*)pb;
            pf[1][g][1] = *(const f32x4*)(pb + 4);
        }
    };
    auto write_lds = [&]() {
#pragma unroll
        for (int g = 0; g < 4; ++g) {
            union { unsigned short s[8]; short8 v; } pka, pkb;
#pragma unroll
            for (int j = 0; j < 4; ++j) {
                pka.s[j] = f2bf(pf[0][g][0][j]);
                pka.s[4 + j] = f2bf(pf[0][g][1][j]);
                pkb.s[j] = f2bf(pf[1][g][0][j]);
                pkb.s[4 + j] = f2bf(pf[1][g][1][j]);
            }
            *(short8*)&As[(srow + g * 32) * 64 + slot8] = pka.v;
            *(short8*)&Bs[(srow + g * 32) * 64 + slot8] = pkb.v;
        }
    };

    f32x4 acc[4][4] = {};

    auto compute = [&]() {
#pragma unroll
        for (int ks = 0; ks < 2; ++ks) {
            short8 af[4], bfr[4];
#pragma unroll
            for (int mi = 0; mi < 4; ++mi) {
                int ar = wr * 64 + mi * 16 + llo;
                int slot = ((ks << 2) + lhi) ^ (ar & 7);
                af[mi] = *(const short8*)&As[ar * 64 + slot * 8];
            }
#pragma unroll
            for (int ni = 0; ni < 4; ++ni) {
                int br = wc * 64 + ni * 16 + llo;
                int slot = ((ks << 2) + lhi) ^ (br & 7);
                bfr[ni] = *(const short8*)&Bs[br * 64 + slot * 8];
            }
#pragma unroll
            for (int mi = 0; mi < 4; ++mi)
#pragma unroll
                for (int ni = 0; ni < 4; ++ni)
                    acc[mi][ni] = __builtin_amdgcn_mfma_f32_16x16x32_bf16(
                        af[mi], bfr[ni], acc[mi][ni], 0, 0, 0);
        }
    };

    issue(0);
    write_lds();
    __syncthreads();
    for (int k0 = 64; k0 < K; k0 += 64) {
        issue(k0);
        compute();
        __syncthreads();
        write_lds();
        __syncthreads();
    }
    compute();

    const bool last_tile = (m0 == M - 128);
#pragma unroll
    for (int mi = 0; mi < 4; ++mi) {
#pragma unroll
        for (int ni = 0; ni < 4; ++ni) {
            int col = n0 + wc * 64 + ni * 16 + llo;
            int rowb = m0 + wr * 64 + mi * 16 + lhi * 4;
#pragma unroll
            for (int r = 0; r < 4; ++r) {
                int row = rowb + r;
                float v = acc[mi][ni][r] + bias0[(row & 127) * N + col];
                v = fmaxf(v, 0.0f);
                C[(size_t)row * N + col] = v;
                if (last_tile) Clast[(row & 127) * N + col] = v;
            }
        }
    }
}

extern "C" void kernel_launch(void* const* d_in, const int* in_sizes, int n_in,
                              void* d_out, int out_size, void* d_ws, size_t ws_size,
                              hipStream_t stream) {
    const float* x = (const float*)d_in[0];       // (T,B,I)
    const float* hidden = (const float*)d_in[1];  // (B,H)
    const float* W_ih = (const float*)d_in[2];    // (H,I)
    const float* W_hh = (const float*)d_in[3];    // (H,H)
    const float* b_ih = (const float*)d_in[4];    // (H,)
    const float* b_hh = (const float*)d_in[5];    // (H,)

    float* out = (float*)d_out;                              // (T,B,H)
    float* out_last = out + (size_t)T_DIM * B_DIM * H_DIM;   // (B,H)

    // ws layout: [0,512K) biasall f32 ; then Xp (256 tiles) ; Wp (8 tiles)
    float* biasall = (float*)d_ws;
    unsigned short* Xp = (unsigned short*)((char*)d_ws + 512 * 1024);
    unsigned short* Wp = Xp + (size_t)256 * 65536;
    const size_t ws_need = 512 * 1024 + (size_t)(256 + 8) * 65536 * 2;

    // biasall[b][h] = hidden[b].W_hh[h] + b_ih[h] + b_hh[h]  (f32 exact)
    bias_dot<<<dim3(512), dim3(256), 0, stream>>>(hidden, W_hh, b_ih, b_hh, biasall);

    if (ws_size >= ws_need) {
        pack_both<<<dim3(264 * 8192 / 256), dim3(256), 0, stream>>>(x, W_ih, Xp);
        gemm256<<<dim3(512), dim3(512), 0, stream>>>(Xp, Wp, biasall, out, out_last);
    } else {
        gemm_bt<<<dim3(M_DIM / 128 * (H_DIM / 128)), dim3(256), 0, stream>>>(
            x, W_ih, M_DIM, H_DIM, I_DIM, biasall, out, out_last);
    }
}